// Round 4
// baseline (195.590 us; speedup 1.0000x reference)
//
#include <hip/hip_runtime.h>
#include <stdint.h>

#define EPSL 1e-11f

typedef _Float16 h2 __attribute__((ext_vector_type(2)));
typedef _Float16 h8 __attribute__((ext_vector_type(8)));
typedef __attribute__((ext_vector_type(4))) float f32x4;
typedef __attribute__((ext_vector_type(16))) float f32x16;

// ---------------- helpers ----------------
__device__ __forceinline__ uint32_t pk2h(float a, float b) {
    union { h2 h; uint32_t u; } t;
    t.h = (h2){ (_Float16)a, (_Float16)b };
    return t.u;
}
__device__ __forceinline__ uint16_t f2h(float a) {
    union { _Float16 h; uint16_t u; } t; t.h = (_Float16)a; return t.u;
}

__device__ __forceinline__ uint64_t sm64(uint64_t x) {
    x += 0x9E3779B97F4A7C15ULL;
    x = (x ^ (x >> 30)) * 0xBF58476D1CE4E5B9ULL;
    x = (x ^ (x >> 27)) * 0x94D049BB133111EBULL;
    return x ^ (x >> 31);
}

__device__ __forceinline__ uint32_t rowz_of(uint32_t f, int dim, int S, int s) {
    uint32_t b = f & 31u;
    uint32_t r = f >> 5;
    uint32_t d, h, w;
    if (dim == 0) {
        w = r & 7u; h = (r >> 3) & 7u; d = (r >> 6) + (uint32_t)s;
    } else if (dim == 1) {
        w = r & 7u; uint32_t q = r >> 3;
        h = q % (uint32_t)S + (uint32_t)s; d = q / (uint32_t)S;
    } else {
        w = r % (uint32_t)S + (uint32_t)s; uint32_t q = r / (uint32_t)S;
        h = q & 7u; d = q >> 3;
    }
    return b * 512u + d * 64u + h * 8u + w;
}

// ---------------- kernels ----------------

// Merged pre-pass: blocks [0,4096) transpose+cast z/c to row-major fp16
// (vectorized float4 tile fill -- same values, bit-identical to scalar);
// blocks [4096,4288) cast W to B-fragment order; blocks [4288,4293) zero
// accumulators + ticket.
__global__ __launch_bounds__(256) void k_prepall(const float* __restrict__ z,
                                                 const float* __restrict__ c,
                                                 const float* __restrict__ W,
                                                 uint16_t* __restrict__ zh,
                                                 uint16_t* __restrict__ cTh,
                                                 uint16_t* __restrict__ Whf,
                                                 float* sums_s, int* cnts_s) {
    const int bid = blockIdx.x;
    const int t = threadIdx.x;
    if (bid < 4096) {
        __shared__ float tile[32][65];
        const int zz = bid >> 6;
        const int b = zz & 31, isC = zz >> 5;
        const float* src = (isC ? c : z) + (size_t)b * 131072;
        const int p0 = (bid & 7) * 64, ch0 = ((bid >> 3) & 7) * 32;
        #pragma unroll
        for (int it = 0; it < 2; it++) {
            int f = t + it * 256;              // 0..511
            int chv = f >> 4, p4 = (f & 15) * 4;
            float4 v = *(const float4*)(src + (size_t)(ch0 + chv) * 512 + p0 + p4);
            tile[chv][p4 + 0] = v.x; tile[chv][p4 + 1] = v.y;
            tile[chv][p4 + 2] = v.z; tile[chv][p4 + 3] = v.w;
        }
        __syncthreads();
        const int ml = t >> 2, ck = (t & 3) * 8;
        uint4 o;
        o.x = pk2h(tile[ck + 0][ml], tile[ck + 1][ml]);
        o.y = pk2h(tile[ck + 2][ml], tile[ck + 3][ml]);
        o.z = pk2h(tile[ck + 4][ml], tile[ck + 5][ml]);
        o.w = pk2h(tile[ck + 6][ml], tile[ck + 7][ml]);
        uint16_t* dst = isC ? cTh : zh;
        *(uint4*)(dst + (size_t)(b * 512 + p0 + ml) * 256 + ch0 + ck) = o;
    } else if (bid < 4288) {
        const int gid = (bid - 4096) * 4 + (t >> 6);
        const int lane = t & 63;
        const int kk = gid >> 7, rem = gid & 127;
        const int ks2 = rem >> 3, ot = rem & 7;
        const int o = ot * 32 + (lane & 31);
        const int cc = ks2 * 16 + (lane >> 5) * 8;
        const float* src = W + ((size_t)kk * 256 + o) * 256 + cc;
        float4 v0 = *(const float4*)src;
        float4 v1 = *(const float4*)(src + 4);
        uint4 out = make_uint4(pk2h(v0.x, v0.y), pk2h(v0.z, v0.w),
                               pk2h(v1.x, v1.y), pk2h(v1.z, v1.w));
        *(uint4*)(Whf + (size_t)gid * 512 + lane * 8) = out;
    } else {
        int t2 = (bid - 4288) * 256 + t;
        if (t2 < 1153) {                       // 1152 slots + ticket
            if (t2 < 1152) sums_s[t2] = 0.f;
            cnts_s[t2] = 0;
        }
    }
}

// ZWh[kk][m][o] fp16 via 32x32x16 MFMA.
// v3-fp16: K-step 64 (32 MFMAs per barrier, 4 steps), 2x32KB DMA double
// buffer, fp16 epilogue reusing staging LDS. Same per-accumulator MFMA
// order as v2 (k-chunks ascending) -> bit-identical output.
__global__ __launch_bounds__(256, 2) void k_gemm(const uint16_t* __restrict__ zh,
                                                 const uint16_t* __restrict__ Whf,
                                                 uint16_t* __restrict__ ZWh) {
    __shared__ __align__(16) uint16_t smem[32768];   // 64 KB
    const int kk = blockIdx.y;
    const int t = threadIdx.x, lane = t & 63, wv = t >> 6;
    const int m0 = blockIdx.x * 128 + wv * 32;
    const int col = lane & 31, hl = lane >> 5;
    const uint16_t* W32 = Whf + (size_t)kk * 65536;
    const uint16_t* A0 = zh + (size_t)(m0 + col) * 256 + hl * 8;

    f32x16 acc[8];
    #pragma unroll
    for (int i = 0; i < 8; i++)
        #pragma unroll
        for (int jj = 0; jj < 16; jj++) acc[i][jj] = 0.f;

    // stage K=64 chunk sk (32 KB) into half buf_; wave wv covers 8 KB
    #define BSTAGE(sk_, buf_) { \
        const char* gb_ = (const char*)W32 + (size_t)(sk_) * 32768 + wv * 8192 + lane * 16; \
        char* lb_ = (char*)smem + (buf_) * 32768 + wv * 8192; \
        _Pragma("unroll") \
        for (int i_ = 0; i_ < 8; i_++) \
            __builtin_amdgcn_global_load_lds( \
                (const __attribute__((address_space(1))) void*)(gb_ + i_ * 1024), \
                (__attribute__((address_space(3))) void*)(lb_ + i_ * 1024), 16, 0, 0); \
    }

    BSTAGE(0, 0);
    asm volatile("s_waitcnt vmcnt(0)" ::: "memory");
    __syncthreads();
    for (int sk = 0; sk < 4; sk++) {
        if (sk < 3) BSTAGE(sk + 1, (sk + 1) & 1);
        const uint16_t* Bb = smem + (sk & 1) * 16384;
        #pragma unroll
        for (int half = 0; half < 4; half++) {
            h8 a = *(const h8*)(A0 + (sk * 4 + half) * 16);
            const uint16_t* Bh = Bb + half * 4096;
            #pragma unroll
            for (int ot = 0; ot < 8; ot++) {
                h8 bv = *(const h8*)(&Bh[ot * 512 + lane * 8]);
                acc[ot] = __builtin_amdgcn_mfma_f32_32x32x16_f16(a, bv, acc[ot], 0, 0, 0);
            }
        }
        asm volatile("s_waitcnt vmcnt(0)" ::: "memory");
        __syncthreads();
    }
    #undef BSTAGE

    // fp16 epilogue: per-wave 8 KB tile in (reused) staging LDS
    uint16_t* Lb = smem + wv * 4096;
    uint16_t* dstbase = ZWh + ((size_t)kk * 16384 + m0) * 256;
    #pragma unroll
    for (int hh = 0; hh < 2; hh++) {
        #pragma unroll
        for (int ot = 0; ot < 8; ot++)
            #pragma unroll
            for (int rg = 0; rg < 8; rg++) {
                int reg = hh * 8 + rg;
                int row = (reg & 3) + 8 * (reg >> 2) + 4 * hl;
                Lb[(row - hh * 16) * 256 + ot * 32 + col] = f2h(acc[ot][reg]);
            }
        const uint4* Lr = (const uint4*)Lb;
        uint4* dst = (uint4*)(dstbase + hh * 16 * 256);
        #pragma unroll
        for (int i = 0; i < 8; i++)
            dst[i * 64 + lane] = Lr[i * 64 + lane];
    }
}

// Score v12 (round-2 bit-exact numerics) + fused final reduction:
// the last block to finish (device-scope ticket) replays k_final's exact
// summation order, reading slots via atomicAdd(p,0) so reads are served at
// the device coherence point (per-XCD L2s are not cross-coherent).
__global__ __launch_bounds__(256, 4) void k_score(const uint16_t* __restrict__ ZWh,
                                                  const uint16_t* __restrict__ cTh,
                                                  const int* __restrict__ ign,
                                                  float* sums_s, int* cnts_s,
                                                  int* ticket, float* out) {
    __shared__ float sbuf[4][288];
    __shared__ float wsum[4], wcnt[4];
    __shared__ int isLast;
    int bid = blockIdx.x;
    int kk = 0, cum = 0;
    for (;;) { int nb = 96 * (6 - kk); if (bid < cum + nb) break; cum += nb; kk++; }
    const int S = 6 - kk, T = S * 2048, s = kk + 2;
    const uint16_t* ZW = ZWh + (size_t)kk * 16384 * 256;

    const int local = bid - cum;
    const int dim = local / (32 * S);
    const int loc2 = local - dim * 32 * S;
    const int term = dim * 6 + kk;

    const int t = threadIdx.x, lane = t & 63, wv = t >> 6;
    const int lm = lane & 15, lq = lane >> 4;
    const uint32_t gidx = (uint32_t)(loc2 * 4 + wv);
    const uint32_t b = gidx & 31u;
    const uint32_t rb = gidx >> 5;
    const uint32_t r = rb * 16u + (uint32_t)lm;   // row slot lm's position

    uint32_t d, h, w;
    if (dim == 0)      { w = r & 7u; h = (r >> 3) & 7u; d = r >> 6; }
    else if (dim == 1) { w = r & 7u; uint32_t qq = r >> 3; h = qq % (uint32_t)S; d = qq / (uint32_t)S; }
    else               { w = r % (uint32_t)S; uint32_t qq = r / (uint32_t)S; h = qq & 7u; d = qq >> 3; }
    uint32_t pc = d * 64u + h * 8u + w;
    uint32_t pz = pc + (dim == 0 ? (uint32_t)s * 64u : dim == 1 ? (uint32_t)s * 8u : (uint32_t)s);
    uint32_t rowc = b * 512u + pc;
    uint32_t rowz = b * 512u + pz;

    // one shared negative row per slot lm (same sm64 stream family, set j=0)
    uint64_t x = sm64(((uint64_t)term << 40) +
                      (uint64_t)gidx * 128u + (uint64_t)lm);
    uint32_t nrow = rowz_of((uint32_t)(x >> 32) % (uint32_t)T, dim, S, s);

    int mok = (ign[rowc] + ign[rowz]) == 0;

    // per-lane fragment bases: row (lane&15), 8 fp16 at k = ks*32 + lq*8
    const uint16_t* cA = cTh + (size_t)rowc * 256 + lq * 8;
    const uint16_t* pB = ZW + (size_t)rowz * 256 + lq * 8;
    const uint16_t* nB = ZW + (size_t)nrow * 256 + lq * 8;

    h8 af[8], pf[8], nf[8];
    #pragma unroll
    for (int ks = 0; ks < 8; ks++) af[ks] = *(const h8*)(cA + ks * 32);
    #pragma unroll
    for (int ks = 0; ks < 8; ks++) pf[ks] = *(const h8*)(pB + ks * 32);
    #pragma unroll
    for (int ks = 0; ks < 8; ks++) nf[ks] = *(const h8*)(nB + ks * 32);

    f32x4 accp = (f32x4){0.f, 0.f, 0.f, 0.f};
    f32x4 accn = (f32x4){0.f, 0.f, 0.f, 0.f};
    #pragma unroll
    for (int ks = 0; ks < 8; ks++)
        accp = __builtin_amdgcn_mfma_f32_16x16x32_f16(af[ks], pf[ks], accp, 0, 0, 0);
    #pragma unroll
    for (int ks = 0; ks < 8; ks++)
        accn = __builtin_amdgcn_mfma_f32_16x16x32_f16(af[ks], nf[ks], accn, 0, 0, 0);

    // scatter scores: D[m][n] with m = lq*4+reg, n = lm
    float* Sb = sbuf[wv];
    #pragma unroll
    for (int rg = 0; rg < 4; rg++)
        Sb[(lq * 4 + rg) * 17 + lm] = accn[rg];
    if ((lm >> 2) == lq) Sb[272 + lm] = accp[lm & 3];

    // softmax-NLL for position p = lm (4x redundant across lq)
    float dpos = Sb[272 + lm];
    float mx = dpos;
    float scn[16];
    #pragma unroll
    for (int n = 0; n < 16; n++) { scn[n] = Sb[lm * 17 + n]; mx = fmaxf(mx, scn[n]); }
    float e0 = __expf(dpos - mx), sum = e0;
    #pragma unroll
    for (int n = 0; n < 16; n++) sum += __expf(scn[n] - mx);
    float nll = -__logf(e0 / sum + EPSL);

    float v = mok ? nll : 0.f;
    float cm = mok ? 1.f : 0.f;
    #pragma unroll
    for (int st = 1; st < 64; st <<= 1) {
        v  += __shfl_xor(v, st, 64);
        cm += __shfl_xor(cm, st, 64);
    }
    if (lane == 0) { wsum[wv] = v * 0.25f; wcnt[wv] = cm * 0.25f; }
    __syncthreads();
    if (t == 0) {
        float sv = wsum[0] + wsum[1] + wsum[2] + wsum[3];
        float cv = wcnt[0] + wcnt[1] + wcnt[2] + wcnt[3];
        int slot = blockIdx.x & 63;
        atomicAdd(&sums_s[term * 64 + slot], sv);
        atomicAdd(&cnts_s[term * 64 + slot], (int)(cv + 0.5f));
        __threadfence();
        int done = atomicAdd(ticket, 1);
        isLast = (done == 2015);
    }
    __syncthreads();
    if (isLast) {
        __shared__ float ratio[18];
        if (t < 18) {
            float sv = 0.f; int cv = 0;
            #pragma unroll 8
            for (int i = 0; i < 64; i++) {
                sv += atomicAdd(&sums_s[t * 64 + i], 0.f);
                cv += atomicAdd(&cnts_s[t * 64 + i], 0);
            }
            ratio[t] = sv / (float)cv;
        }
        __syncthreads();
        if (t == 0) {
            float tot = 0.f;
            #pragma unroll
            for (int i = 0; i < 18; i++) tot += ratio[i];
            out[0] = tot / 18.f;
        }
    }
}

// ---------------- launch ----------------
extern "C" void kernel_launch(void* const* d_in, const int* in_sizes, int n_in,
                              void* d_out, int out_size, void* d_ws, size_t ws_size,
                              hipStream_t stream) {
    const float* z   = (const float*)d_in[0];
    const float* c   = (const float*)d_in[1];
    const int*   ign = (const int*)d_in[2];
    const float* Wk  = (const float*)d_in[3];

    float* sums_s = (float*)d_ws;                           // 18*64 floats
    int*   cnts_s = (int*)((char*)d_ws + 4608);             // 18*64 ints + ticket
    int*   ticket = cnts_s + 1152;
    uint16_t* zh  = (uint16_t*)((char*)d_ws + 65536);       // 8 MiB row-major fp16
    uint16_t* cTh = zh  + (size_t)16384 * 256;              // 8 MiB row-major fp16
    uint16_t* Whf = cTh + (size_t)16384 * 256;              // 768 KiB B-frag order
    uint16_t* ZWh = Whf + (size_t)6 * 65536;                // 48 MiB row-major fp16

    hipLaunchKernelGGL(k_prepall, dim3(4293), dim3(256), 0, stream,
                       z, c, Wk, zh, cTh, Whf, sums_s, cnts_s);
    hipLaunchKernelGGL(k_gemm, dim3(128, 6), dim3(256), 0, stream, zh, Whf, ZWh);
    hipLaunchKernelGGL(k_score, dim3(2016), dim3(256), 0, stream,
                       ZWh, cTh, ign, sums_s, cnts_s, ticket, (float*)d_out);
}

// Round 6
// 132.557 us; speedup vs baseline: 1.4755x; 1.4755x over previous
//
#include <hip/hip_runtime.h>
#include <stdint.h>

#define EPSL 1e-11f

typedef _Float16 h2 __attribute__((ext_vector_type(2)));
typedef _Float16 h8 __attribute__((ext_vector_type(8)));
typedef __attribute__((ext_vector_type(4))) float f32x4;
typedef __attribute__((ext_vector_type(16))) float f32x16;

// ---------------- helpers ----------------
__device__ __forceinline__ uint32_t pk2h(float a, float b) {
    union { h2 h; uint32_t u; } t;
    t.h = (h2){ (_Float16)a, (_Float16)b };
    return t.u;
}
__device__ __forceinline__ uint16_t f2h(float a) {
    union { _Float16 h; uint16_t u; } t; t.h = (_Float16)a; return t.u;
}

__device__ __forceinline__ uint64_t sm64(uint64_t x) {
    x += 0x9E3779B97F4A7C15ULL;
    x = (x ^ (x >> 30)) * 0xBF58476D1CE4E5B9ULL;
    x = (x ^ (x >> 27)) * 0x94D049BB133111EBULL;
    return x ^ (x >> 31);
}

__device__ __forceinline__ uint32_t rowz_of(uint32_t f, int dim, int S, int s) {
    uint32_t b = f & 31u;
    uint32_t r = f >> 5;
    uint32_t d, h, w;
    if (dim == 0) {
        w = r & 7u; h = (r >> 3) & 7u; d = (r >> 6) + (uint32_t)s;
    } else if (dim == 1) {
        w = r & 7u; uint32_t q = r >> 3;
        h = q % (uint32_t)S + (uint32_t)s; d = q / (uint32_t)S;
    } else {
        w = r % (uint32_t)S + (uint32_t)s; uint32_t q = r / (uint32_t)S;
        h = q & 7u; d = q >> 3;
    }
    return b * 512u + d * 64u + h * 8u + w;
}

// ---------------- kernels ----------------

// Merged pre-pass: blocks [0,4096) transpose+cast z/c to row-major fp16
// (vectorized float4 tile fill -- bit-identical to scalar); blocks
// [4096,4288) cast W to B-fragment order; blocks [4288,4293) zero accum.
__global__ __launch_bounds__(256) void k_prepall(const float* __restrict__ z,
                                                 const float* __restrict__ c,
                                                 const float* __restrict__ W,
                                                 uint16_t* __restrict__ zh,
                                                 uint16_t* __restrict__ cTh,
                                                 uint16_t* __restrict__ Whf,
                                                 float* sums_s, int* cnts_s) {
    const int bid = blockIdx.x;
    const int t = threadIdx.x;
    if (bid < 4096) {
        __shared__ float tile[32][65];
        const int zz = bid >> 6;
        const int b = zz & 31, isC = zz >> 5;
        const float* src = (isC ? c : z) + (size_t)b * 131072;
        const int p0 = (bid & 7) * 64, ch0 = ((bid >> 3) & 7) * 32;
        #pragma unroll
        for (int it = 0; it < 2; it++) {
            int f = t + it * 256;              // 0..511
            int chv = f >> 4, p4 = (f & 15) * 4;
            float4 v = *(const float4*)(src + (size_t)(ch0 + chv) * 512 + p0 + p4);
            tile[chv][p4 + 0] = v.x; tile[chv][p4 + 1] = v.y;
            tile[chv][p4 + 2] = v.z; tile[chv][p4 + 3] = v.w;
        }
        __syncthreads();
        const int ml = t >> 2, ck = (t & 3) * 8;
        uint4 o;
        o.x = pk2h(tile[ck + 0][ml], tile[ck + 1][ml]);
        o.y = pk2h(tile[ck + 2][ml], tile[ck + 3][ml]);
        o.z = pk2h(tile[ck + 4][ml], tile[ck + 5][ml]);
        o.w = pk2h(tile[ck + 6][ml], tile[ck + 7][ml]);
        uint16_t* dst = isC ? cTh : zh;
        *(uint4*)(dst + (size_t)(b * 512 + p0 + ml) * 256 + ch0 + ck) = o;
    } else if (bid < 4288) {
        const int gid = (bid - 4096) * 4 + (t >> 6);
        const int lane = t & 63;
        const int kk = gid >> 7, rem = gid & 127;
        const int ks2 = rem >> 3, ot = rem & 7;
        const int o = ot * 32 + (lane & 31);
        const int cc = ks2 * 16 + (lane >> 5) * 8;
        const float* src = W + ((size_t)kk * 256 + o) * 256 + cc;
        float4 v0 = *(const float4*)src;
        float4 v1 = *(const float4*)(src + 4);
        uint4 out = make_uint4(pk2h(v0.x, v0.y), pk2h(v0.z, v0.w),
                               pk2h(v1.x, v1.y), pk2h(v1.z, v1.w));
        *(uint4*)(Whf + (size_t)gid * 512 + lane * 8) = out;
    } else {
        int t2 = (bid - 4288) * 256 + t;
        if (t2 < 1152) { sums_s[t2] = 0.f; cnts_s[t2] = 0; }
    }
}

// ZWh[kk][m][o] fp16 via 32x32x16 MFMA.
// v3-fp16: K-step 64 (32 MFMAs per barrier, 4 steps), 2x32KB DMA double
// buffer, fp16 epilogue reusing staging LDS. Same per-accumulator MFMA
// order as v2 (k-chunks ascending) -> bit-identical output.
__global__ __launch_bounds__(256, 2) void k_gemm(const uint16_t* __restrict__ zh,
                                                 const uint16_t* __restrict__ Whf,
                                                 uint16_t* __restrict__ ZWh) {
    __shared__ __align__(16) uint16_t smem[32768];   // 64 KB
    const int kk = blockIdx.y;
    const int t = threadIdx.x, lane = t & 63, wv = t >> 6;
    const int m0 = blockIdx.x * 128 + wv * 32;
    const int col = lane & 31, hl = lane >> 5;
    const uint16_t* W32 = Whf + (size_t)kk * 65536;
    const uint16_t* A0 = zh + (size_t)(m0 + col) * 256 + hl * 8;

    f32x16 acc[8];
    #pragma unroll
    for (int i = 0; i < 8; i++)
        #pragma unroll
        for (int jj = 0; jj < 16; jj++) acc[i][jj] = 0.f;

    // stage K=64 chunk sk (32 KB) into half buf_; wave wv covers 8 KB
    #define BSTAGE(sk_, buf_) { \
        const char* gb_ = (const char*)W32 + (size_t)(sk_) * 32768 + wv * 8192 + lane * 16; \
        char* lb_ = (char*)smem + (buf_) * 32768 + wv * 8192; \
        _Pragma("unroll") \
        for (int i_ = 0; i_ < 8; i_++) \
            __builtin_amdgcn_global_load_lds( \
                (const __attribute__((address_space(1))) void*)(gb_ + i_ * 1024), \
                (__attribute__((address_space(3))) void*)(lb_ + i_ * 1024), 16, 0, 0); \
    }

    BSTAGE(0, 0);
    asm volatile("s_waitcnt vmcnt(0)" ::: "memory");
    __syncthreads();
    for (int sk = 0; sk < 4; sk++) {
        if (sk < 3) BSTAGE(sk + 1, (sk + 1) & 1);
        const uint16_t* Bb = smem + (sk & 1) * 16384;
        #pragma unroll
        for (int half = 0; half < 4; half++) {
            h8 a = *(const h8*)(A0 + (sk * 4 + half) * 16);
            const uint16_t* Bh = Bb + half * 4096;
            #pragma unroll
            for (int ot = 0; ot < 8; ot++) {
                h8 bv = *(const h8*)(&Bh[ot * 512 + lane * 8]);
                acc[ot] = __builtin_amdgcn_mfma_f32_32x32x16_f16(a, bv, acc[ot], 0, 0, 0);
            }
        }
        asm volatile("s_waitcnt vmcnt(0)" ::: "memory");
        __syncthreads();
    }
    #undef BSTAGE

    // fp16 epilogue: per-wave 8 KB tile in (reused) staging LDS
    uint16_t* Lb = smem + wv * 4096;
    uint16_t* dstbase = ZWh + ((size_t)kk * 16384 + m0) * 256;
    #pragma unroll
    for (int hh = 0; hh < 2; hh++) {
        #pragma unroll
        for (int ot = 0; ot < 8; ot++)
            #pragma unroll
            for (int rg = 0; rg < 8; rg++) {
                int reg = hh * 8 + rg;
                int row = (reg & 3) + 8 * (reg >> 2) + 4 * hl;
                Lb[(row - hh * 16) * 256 + ot * 32 + col] = f2h(acc[ot][reg]);
            }
        const uint4* Lr = (const uint4*)Lb;
        uint4* dst = (uint4*)(dstbase + hh * 16 * 256);
        #pragma unroll
        for (int i = 0; i < 8; i++)
            dst[i * 64 + lane] = Lr[i * 64 + lane];
    }
}

// Score v12 -- verbatim round-2 version (no ticket, no fence, no tail).
// R4 lesson: the fused-final tail (isLast + __syncthreads in divergent CF +
// __threadfence) collapsed codegen to VGPR=28 (fragments in scratch) and
// tripled runtime. Keep the epilogue as a separate tiny kernel.
__global__ __launch_bounds__(256, 4) void k_score(const uint16_t* __restrict__ ZWh,
                                                  const uint16_t* __restrict__ cTh,
                                                  const int* __restrict__ ign,
                                                  float* sums_s, int* cnts_s) {
    __shared__ float sbuf[4][288];
    __shared__ float wsum[4], wcnt[4];
    int bid = blockIdx.x;
    int kk = 0, cum = 0;
    for (;;) { int nb = 96 * (6 - kk); if (bid < cum + nb) break; cum += nb; kk++; }
    const int S = 6 - kk, T = S * 2048, s = kk + 2;
    const uint16_t* ZW = ZWh + (size_t)kk * 16384 * 256;

    const int local = bid - cum;
    const int dim = local / (32 * S);
    const int loc2 = local - dim * 32 * S;
    const int term = dim * 6 + kk;

    const int t = threadIdx.x, lane = t & 63, wv = t >> 6;
    const int lm = lane & 15, lq = lane >> 4;
    const uint32_t gidx = (uint32_t)(loc2 * 4 + wv);
    const uint32_t b = gidx & 31u;
    const uint32_t rb = gidx >> 5;
    const uint32_t r = rb * 16u + (uint32_t)lm;   // row slot lm's position

    uint32_t d, h, w;
    if (dim == 0)      { w = r & 7u; h = (r >> 3) & 7u; d = r >> 6; }
    else if (dim == 1) { w = r & 7u; uint32_t qq = r >> 3; h = qq % (uint32_t)S; d = qq / (uint32_t)S; }
    else               { w = r % (uint32_t)S; uint32_t qq = r / (uint32_t)S; h = qq & 7u; d = qq >> 3; }
    uint32_t pc = d * 64u + h * 8u + w;
    uint32_t pz = pc + (dim == 0 ? (uint32_t)s * 64u : dim == 1 ? (uint32_t)s * 8u : (uint32_t)s);
    uint32_t rowc = b * 512u + pc;
    uint32_t rowz = b * 512u + pz;

    // one shared negative row per slot lm (same sm64 stream family, set j=0)
    uint64_t x = sm64(((uint64_t)term << 40) +
                      (uint64_t)gidx * 128u + (uint64_t)lm);
    uint32_t nrow = rowz_of((uint32_t)(x >> 32) % (uint32_t)T, dim, S, s);

    int mok = (ign[rowc] + ign[rowz]) == 0;

    // per-lane fragment bases: row (lane&15), 8 fp16 at k = ks*32 + lq*8
    const uint16_t* cA = cTh + (size_t)rowc * 256 + lq * 8;
    const uint16_t* pB = ZW + (size_t)rowz * 256 + lq * 8;
    const uint16_t* nB = ZW + (size_t)nrow * 256 + lq * 8;

    h8 af[8], pf[8], nf[8];
    #pragma unroll
    for (int ks = 0; ks < 8; ks++) af[ks] = *(const h8*)(cA + ks * 32);
    #pragma unroll
    for (int ks = 0; ks < 8; ks++) pf[ks] = *(const h8*)(pB + ks * 32);
    #pragma unroll
    for (int ks = 0; ks < 8; ks++) nf[ks] = *(const h8*)(nB + ks * 32);

    f32x4 accp = (f32x4){0.f, 0.f, 0.f, 0.f};
    f32x4 accn = (f32x4){0.f, 0.f, 0.f, 0.f};
    #pragma unroll
    for (int ks = 0; ks < 8; ks++)
        accp = __builtin_amdgcn_mfma_f32_16x16x32_f16(af[ks], pf[ks], accp, 0, 0, 0);
    #pragma unroll
    for (int ks = 0; ks < 8; ks++)
        accn = __builtin_amdgcn_mfma_f32_16x16x32_f16(af[ks], nf[ks], accn, 0, 0, 0);

    // scatter scores: D[m][n] with m = lq*4+reg, n = lm
    float* Sb = sbuf[wv];
    #pragma unroll
    for (int rg = 0; rg < 4; rg++)
        Sb[(lq * 4 + rg) * 17 + lm] = accn[rg];
    if ((lm >> 2) == lq) Sb[272 + lm] = accp[lm & 3];

    // softmax-NLL for position p = lm (4x redundant across lq)
    float dpos = Sb[272 + lm];
    float mx = dpos;
    float scn[16];
    #pragma unroll
    for (int n = 0; n < 16; n++) { scn[n] = Sb[lm * 17 + n]; mx = fmaxf(mx, scn[n]); }
    float e0 = __expf(dpos - mx), sum = e0;
    #pragma unroll
    for (int n = 0; n < 16; n++) sum += __expf(scn[n] - mx);
    float nll = -__logf(e0 / sum + EPSL);

    float v = mok ? nll : 0.f;
    float cm = mok ? 1.f : 0.f;
    #pragma unroll
    for (int st = 1; st < 64; st <<= 1) {
        v  += __shfl_xor(v, st, 64);
        cm += __shfl_xor(cm, st, 64);
    }
    if (lane == 0) { wsum[wv] = v * 0.25f; wcnt[wv] = cm * 0.25f; }
    __syncthreads();
    if (t == 0) {
        float sv = wsum[0] + wsum[1] + wsum[2] + wsum[3];
        float cv = wcnt[0] + wcnt[1] + wcnt[2] + wcnt[3];
        int slot = blockIdx.x & 63;
        atomicAdd(&sums_s[term * 64 + slot], sv);
        atomicAdd(&cnts_s[term * 64 + slot], (int)(cv + 0.5f));
    }
}

__global__ void k_final(const float* __restrict__ sums_s, const int* __restrict__ cnts_s,
                        float* __restrict__ out) {
    __shared__ float ratio[18];
    int t = threadIdx.x;
    if (t < 18) {
        float sv = 0.f; int cv = 0;
        #pragma unroll 8
        for (int i = 0; i < 64; i++) { sv += sums_s[t * 64 + i]; cv += cnts_s[t * 64 + i]; }
        ratio[t] = sv / (float)cv;
    }
    __syncthreads();
    if (t == 0) {
        float tot = 0.f;
        #pragma unroll
        for (int i = 0; i < 18; i++) tot += ratio[i];
        out[0] = tot / 18.f;
    }
}

// ---------------- launch ----------------
extern "C" void kernel_launch(void* const* d_in, const int* in_sizes, int n_in,
                              void* d_out, int out_size, void* d_ws, size_t ws_size,
                              hipStream_t stream) {
    const float* z   = (const float*)d_in[0];
    const float* c   = (const float*)d_in[1];
    const int*   ign = (const int*)d_in[2];
    const float* Wk  = (const float*)d_in[3];

    float* sums_s = (float*)d_ws;                           // 18*64 floats
    int*   cnts_s = (int*)((char*)d_ws + 4608);             // 18*64 ints
    uint16_t* zh  = (uint16_t*)((char*)d_ws + 65536);       // 8 MiB row-major fp16
    uint16_t* cTh = zh  + (size_t)16384 * 256;              // 8 MiB row-major fp16
    uint16_t* Whf = cTh + (size_t)16384 * 256;              // 768 KiB B-frag order
    uint16_t* ZWh = Whf + (size_t)6 * 65536;                // 48 MiB row-major fp16

    hipLaunchKernelGGL(k_prepall, dim3(4293), dim3(256), 0, stream,
                       z, c, Wk, zh, cTh, Whf, sums_s, cnts_s);
    hipLaunchKernelGGL(k_gemm, dim3(128, 6), dim3(256), 0, stream, zh, Whf, ZWh);
    hipLaunchKernelGGL(k_score, dim3(2016), dim3(256), 0, stream, ZWh, cTh, ign, sums_s, cnts_s);
    hipLaunchKernelGGL(k_final, dim3(1), dim3(64), 0, stream, sums_s, cnts_s, (float*)d_out);
}

// Round 7
// 131.388 us; speedup vs baseline: 1.4886x; 1.0089x over previous
//
#include <hip/hip_runtime.h>
#include <stdint.h>

#define EPSL 1e-11f

typedef _Float16 h2 __attribute__((ext_vector_type(2)));
typedef _Float16 h8 __attribute__((ext_vector_type(8)));
typedef __attribute__((ext_vector_type(4))) float f32x4;
typedef __attribute__((ext_vector_type(16))) float f32x16;

// ---------------- helpers ----------------
__device__ __forceinline__ uint32_t pk2h(float a, float b) {
    union { h2 h; uint32_t u; } t;
    t.h = (h2){ (_Float16)a, (_Float16)b };
    return t.u;
}
__device__ __forceinline__ uint16_t f2h(float a) {
    union { _Float16 h; uint16_t u; } t; t.h = (_Float16)a; return t.u;
}

__device__ __forceinline__ uint64_t sm64(uint64_t x) {
    x += 0x9E3779B97F4A7C15ULL;
    x = (x ^ (x >> 30)) * 0xBF58476D1CE4E5B9ULL;
    x = (x ^ (x >> 27)) * 0x94D049BB133111EBULL;
    return x ^ (x >> 31);
}

__device__ __forceinline__ uint32_t rowz_of(uint32_t f, int dim, int S, int s) {
    uint32_t b = f & 31u;
    uint32_t r = f >> 5;
    uint32_t d, h, w;
    if (dim == 0) {
        w = r & 7u; h = (r >> 3) & 7u; d = (r >> 6) + (uint32_t)s;
    } else if (dim == 1) {
        w = r & 7u; uint32_t q = r >> 3;
        h = q % (uint32_t)S + (uint32_t)s; d = q / (uint32_t)S;
    } else {
        w = r % (uint32_t)S + (uint32_t)s; uint32_t q = r / (uint32_t)S;
        h = q & 7u; d = q >> 3;
    }
    return b * 512u + d * 64u + h * 8u + w;
}

// ---------------- kernels ----------------

// Merged pre-pass: blocks [0,4096) transpose+cast z/c to row-major fp16
// (vectorized float4 tile fill -- bit-identical to scalar); blocks
// [4096,4288) cast W to B-fragment order; blocks [4288,4293) zero accum.
__global__ __launch_bounds__(256) void k_prepall(const float* __restrict__ z,
                                                 const float* __restrict__ c,
                                                 const float* __restrict__ W,
                                                 uint16_t* __restrict__ zh,
                                                 uint16_t* __restrict__ cTh,
                                                 uint16_t* __restrict__ Whf,
                                                 float* sums_s, int* cnts_s) {
    const int bid = blockIdx.x;
    const int t = threadIdx.x;
    if (bid < 4096) {
        __shared__ float tile[32][65];
        const int zz = bid >> 6;
        const int b = zz & 31, isC = zz >> 5;
        const float* src = (isC ? c : z) + (size_t)b * 131072;
        const int p0 = (bid & 7) * 64, ch0 = ((bid >> 3) & 7) * 32;
        #pragma unroll
        for (int it = 0; it < 2; it++) {
            int f = t + it * 256;              // 0..511
            int chv = f >> 4, p4 = (f & 15) * 4;
            float4 v = *(const float4*)(src + (size_t)(ch0 + chv) * 512 + p0 + p4);
            tile[chv][p4 + 0] = v.x; tile[chv][p4 + 1] = v.y;
            tile[chv][p4 + 2] = v.z; tile[chv][p4 + 3] = v.w;
        }
        __syncthreads();
        const int ml = t >> 2, ck = (t & 3) * 8;
        uint4 o;
        o.x = pk2h(tile[ck + 0][ml], tile[ck + 1][ml]);
        o.y = pk2h(tile[ck + 2][ml], tile[ck + 3][ml]);
        o.z = pk2h(tile[ck + 4][ml], tile[ck + 5][ml]);
        o.w = pk2h(tile[ck + 6][ml], tile[ck + 7][ml]);
        uint16_t* dst = isC ? cTh : zh;
        *(uint4*)(dst + (size_t)(b * 512 + p0 + ml) * 256 + ch0 + ck) = o;
    } else if (bid < 4288) {
        const int gid = (bid - 4096) * 4 + (t >> 6);
        const int lane = t & 63;
        const int kk = gid >> 7, rem = gid & 127;
        const int ks2 = rem >> 3, ot = rem & 7;
        const int o = ot * 32 + (lane & 31);
        const int cc = ks2 * 16 + (lane >> 5) * 8;
        const float* src = W + ((size_t)kk * 256 + o) * 256 + cc;
        float4 v0 = *(const float4*)src;
        float4 v1 = *(const float4*)(src + 4);
        uint4 out = make_uint4(pk2h(v0.x, v0.y), pk2h(v0.z, v0.w),
                               pk2h(v1.x, v1.y), pk2h(v1.z, v1.w));
        *(uint4*)(Whf + (size_t)gid * 512 + lane * 8) = out;
    } else {
        int t2 = (bid - 4288) * 256 + t;
        if (t2 < 1152) { sums_s[t2] = 0.f; cnts_s[t2] = 0; }
    }
}

// ZWh[kk][m][o] fp16 via 32x32x16 MFMA.
// v4: round-2 K=32 structure (16 MFMAs/barrier, 8 steps, 2x16KB DMA double
// buffer, epilogue reuses staging LDS) with occupancy PINNED at 3 blocks/CU
// via __launch_bounds__(256,3): VGPR cap 170 (acc 128 + ~35 fits), LDS
// 3x32KB=96KB <= 160KB, grid 768 = 3/CU x 256 CU exactly. R6 lesson: the
// K=64 64KB variant capped occupancy at 2 blocks/CU and lost ~3.5us.
__global__ __launch_bounds__(256, 3) void k_gemm(const uint16_t* __restrict__ zh,
                                                 const uint16_t* __restrict__ Whf,
                                                 uint16_t* __restrict__ ZWh) {
    __shared__ __align__(16) uint16_t smem[16384];   // 32 KB: 2x16KB staging | 4x8KB epilogue
    const int kk = blockIdx.y;
    const int t = threadIdx.x, lane = t & 63, wv = t >> 6;
    const int m0 = blockIdx.x * 128 + wv * 32;
    const int col = lane & 31, hl = lane >> 5;
    const uint16_t* W32 = Whf + (size_t)kk * 65536;
    const uint16_t* A0 = zh + (size_t)(m0 + col) * 256 + hl * 8;

    f32x16 acc[8];
    #pragma unroll
    for (int i = 0; i < 8; i++)
        #pragma unroll
        for (int jj = 0; jj < 16; jj++) acc[i][jj] = 0.f;

    // stage the K=32 chunk `sk` (16 KB) into half `buf`; wave wv covers 4 KB
    #define BSTAGE(sk_, buf_) { \
        const char* gb_ = (const char*)W32 + (size_t)(sk_) * 16384 + wv * 4096 + lane * 16; \
        char* lb_ = (char*)smem + (buf_) * 16384 + wv * 4096; \
        _Pragma("unroll") \
        for (int i_ = 0; i_ < 4; i_++) \
            __builtin_amdgcn_global_load_lds( \
                (const __attribute__((address_space(1))) void*)(gb_ + i_ * 1024), \
                (__attribute__((address_space(3))) void*)(lb_ + i_ * 1024), 16, 0, 0); \
    }

    BSTAGE(0, 0);
    asm volatile("s_waitcnt vmcnt(0)" ::: "memory");
    __syncthreads();
    for (int sk = 0; sk < 8; sk++) {
        if (sk < 7) BSTAGE(sk + 1, (sk + 1) & 1);
        const uint16_t* Bb = smem + (sk & 1) * 8192;
        #pragma unroll
        for (int half = 0; half < 2; half++) {
            h8 a = *(const h8*)(A0 + (sk * 2 + half) * 16);
            const uint16_t* Bh = Bb + half * 4096;
            #pragma unroll
            for (int ot = 0; ot < 8; ot++) {
                h8 bv = *(const h8*)(&Bh[ot * 512 + lane * 8]);
                acc[ot] = __builtin_amdgcn_mfma_f32_32x32x16_f16(a, bv, acc[ot], 0, 0, 0);
            }
        }
        asm volatile("s_waitcnt vmcnt(0)" ::: "memory");
        __syncthreads();
    }
    #undef BSTAGE

    // fp16 epilogue: per-wave 8 KB tile in (reused) staging LDS
    uint16_t* Lb = smem + wv * 4096;
    uint16_t* dstbase = ZWh + ((size_t)kk * 16384 + m0) * 256;
    #pragma unroll
    for (int hh = 0; hh < 2; hh++) {
        #pragma unroll
        for (int ot = 0; ot < 8; ot++)
            #pragma unroll
            for (int rg = 0; rg < 8; rg++) {
                int reg = hh * 8 + rg;
                int row = (reg & 3) + 8 * (reg >> 2) + 4 * hl;
                Lb[(row - hh * 16) * 256 + ot * 32 + col] = f2h(acc[ot][reg]);
            }
        const uint4* Lr = (const uint4*)Lb;
        uint4* dst = (uint4*)(dstbase + hh * 16 * 256);
        #pragma unroll
        for (int i = 0; i < 8; i++)
            dst[i * 64 + lane] = Lr[i * 64 + lane];
    }
}

// Score v12 -- verbatim round-2 version (no ticket, no fence, no tail).
// R4 lesson: the fused-final tail (isLast + __syncthreads in divergent CF +
// __threadfence) collapsed codegen to VGPR=28 (fragments in scratch) and
// tripled runtime. Keep the epilogue as a separate tiny kernel.
__global__ __launch_bounds__(256, 4) void k_score(const uint16_t* __restrict__ ZWh,
                                                  const uint16_t* __restrict__ cTh,
                                                  const int* __restrict__ ign,
                                                  float* sums_s, int* cnts_s) {
    __shared__ float sbuf[4][288];
    __shared__ float wsum[4], wcnt[4];
    int bid = blockIdx.x;
    int kk = 0, cum = 0;
    for (;;) { int nb = 96 * (6 - kk); if (bid < cum + nb) break; cum += nb; kk++; }
    const int S = 6 - kk, T = S * 2048, s = kk + 2;
    const uint16_t* ZW = ZWh + (size_t)kk * 16384 * 256;

    const int local = bid - cum;
    const int dim = local / (32 * S);
    const int loc2 = local - dim * 32 * S;
    const int term = dim * 6 + kk;

    const int t = threadIdx.x, lane = t & 63, wv = t >> 6;
    const int lm = lane & 15, lq = lane >> 4;
    const uint32_t gidx = (uint32_t)(loc2 * 4 + wv);
    const uint32_t b = gidx & 31u;
    const uint32_t rb = gidx >> 5;
    const uint32_t r = rb * 16u + (uint32_t)lm;   // row slot lm's position

    uint32_t d, h, w;
    if (dim == 0)      { w = r & 7u; h = (r >> 3) & 7u; d = r >> 6; }
    else if (dim == 1) { w = r & 7u; uint32_t qq = r >> 3; h = qq % (uint32_t)S; d = qq / (uint32_t)S; }
    else               { w = r % (uint32_t)S; uint32_t qq = r / (uint32_t)S; h = qq & 7u; d = qq >> 3; }
    uint32_t pc = d * 64u + h * 8u + w;
    uint32_t pz = pc + (dim == 0 ? (uint32_t)s * 64u : dim == 1 ? (uint32_t)s * 8u : (uint32_t)s);
    uint32_t rowc = b * 512u + pc;
    uint32_t rowz = b * 512u + pz;

    // one shared negative row per slot lm (same sm64 stream family, set j=0)
    uint64_t x = sm64(((uint64_t)term << 40) +
                      (uint64_t)gidx * 128u + (uint64_t)lm);
    uint32_t nrow = rowz_of((uint32_t)(x >> 32) % (uint32_t)T, dim, S, s);

    int mok = (ign[rowc] + ign[rowz]) == 0;

    // per-lane fragment bases: row (lane&15), 8 fp16 at k = ks*32 + lq*8
    const uint16_t* cA = cTh + (size_t)rowc * 256 + lq * 8;
    const uint16_t* pB = ZW + (size_t)rowz * 256 + lq * 8;
    const uint16_t* nB = ZW + (size_t)nrow * 256 + lq * 8;

    h8 af[8], pf[8], nf[8];
    #pragma unroll
    for (int ks = 0; ks < 8; ks++) af[ks] = *(const h8*)(cA + ks * 32);
    #pragma unroll
    for (int ks = 0; ks < 8; ks++) pf[ks] = *(const h8*)(pB + ks * 32);
    #pragma unroll
    for (int ks = 0; ks < 8; ks++) nf[ks] = *(const h8*)(nB + ks * 32);

    f32x4 accp = (f32x4){0.f, 0.f, 0.f, 0.f};
    f32x4 accn = (f32x4){0.f, 0.f, 0.f, 0.f};
    #pragma unroll
    for (int ks = 0; ks < 8; ks++)
        accp = __builtin_amdgcn_mfma_f32_16x16x32_f16(af[ks], pf[ks], accp, 0, 0, 0);
    #pragma unroll
    for (int ks = 0; ks < 8; ks++)
        accn = __builtin_amdgcn_mfma_f32_16x16x32_f16(af[ks], nf[ks], accn, 0, 0, 0);

    // scatter scores: D[m][n] with m = lq*4+reg, n = lm
    float* Sb = sbuf[wv];
    #pragma unroll
    for (int rg = 0; rg < 4; rg++)
        Sb[(lq * 4 + rg) * 17 + lm] = accn[rg];
    if ((lm >> 2) == lq) Sb[272 + lm] = accp[lm & 3];

    // softmax-NLL for position p = lm (4x redundant across lq)
    float dpos = Sb[272 + lm];
    float mx = dpos;
    float scn[16];
    #pragma unroll
    for (int n = 0; n < 16; n++) { scn[n] = Sb[lm * 17 + n]; mx = fmaxf(mx, scn[n]); }
    float e0 = __expf(dpos - mx), sum = e0;
    #pragma unroll
    for (int n = 0; n < 16; n++) sum += __expf(scn[n] - mx);
    float nll = -__logf(e0 / sum + EPSL);

    float v = mok ? nll : 0.f;
    float cm = mok ? 1.f : 0.f;
    #pragma unroll
    for (int st = 1; st < 64; st <<= 1) {
        v  += __shfl_xor(v, st, 64);
        cm += __shfl_xor(cm, st, 64);
    }
    if (lane == 0) { wsum[wv] = v * 0.25f; wcnt[wv] = cm * 0.25f; }
    __syncthreads();
    if (t == 0) {
        float sv = wsum[0] + wsum[1] + wsum[2] + wsum[3];
        float cv = wcnt[0] + wcnt[1] + wcnt[2] + wcnt[3];
        int slot = blockIdx.x & 63;
        atomicAdd(&sums_s[term * 64 + slot], sv);
        atomicAdd(&cnts_s[term * 64 + slot], (int)(cv + 0.5f));
    }
}

__global__ void k_final(const float* __restrict__ sums_s, const int* __restrict__ cnts_s,
                        float* __restrict__ out) {
    __shared__ float ratio[18];
    int t = threadIdx.x;
    if (t < 18) {
        float sv = 0.f; int cv = 0;
        #pragma unroll 8
        for (int i = 0; i < 64; i++) { sv += sums_s[t * 64 + i]; cv += cnts_s[t * 64 + i]; }
        ratio[t] = sv / (float)cv;
    }
    __syncthreads();
    if (t == 0) {
        float tot = 0.f;
        #pragma unroll
        for (int i = 0; i < 18; i++) tot += ratio[i];
        out[0] = tot / 18.f;
    }
}

// ---------------- launch ----------------
extern "C" void kernel_launch(void* const* d_in, const int* in_sizes, int n_in,
                              void* d_out, int out_size, void* d_ws, size_t ws_size,
                              hipStream_t stream) {
    const float* z   = (const float*)d_in[0];
    const float* c   = (const float*)d_in[1];
    const int*   ign = (const int*)d_in[2];
    const float* Wk  = (const float*)d_in[3];

    float* sums_s = (float*)d_ws;                           // 18*64 floats
    int*   cnts_s = (int*)((char*)d_ws + 4608);             // 18*64 ints
    uint16_t* zh  = (uint16_t*)((char*)d_ws + 65536);       // 8 MiB row-major fp16
    uint16_t* cTh = zh  + (size_t)16384 * 256;              // 8 MiB row-major fp16
    uint16_t* Whf = cTh + (size_t)16384 * 256;              // 768 KiB B-frag order
    uint16_t* ZWh = Whf + (size_t)6 * 65536;                // 48 MiB row-major fp16

    hipLaunchKernelGGL(k_prepall, dim3(4293), dim3(256), 0, stream,
                       z, c, Wk, zh, cTh, Whf, sums_s, cnts_s);
    hipLaunchKernelGGL(k_gemm, dim3(128, 6), dim3(256), 0, stream, zh, Whf, ZWh);
    hipLaunchKernelGGL(k_score, dim3(2016), dim3(256), 0, stream, ZWh, cTh, ign, sums_s, cnts_s);
    hipLaunchKernelGGL(k_final, dim3(1), dim3(64), 0, stream, sums_s, cnts_s, (float*)d_out);
}

// Round 8
// 128.095 us; speedup vs baseline: 1.5269x; 1.0257x over previous
//
#include <hip/hip_runtime.h>
#include <stdint.h>

#define EPSL 1e-11f

typedef _Float16 h2 __attribute__((ext_vector_type(2)));
typedef _Float16 h8 __attribute__((ext_vector_type(8)));
typedef __attribute__((ext_vector_type(4))) float f32x4;
typedef __attribute__((ext_vector_type(16))) float f32x16;

// ---------------- helpers ----------------
__device__ __forceinline__ uint32_t pk2h(float a, float b) {
    union { h2 h; uint32_t u; } t;
    t.h = (h2){ (_Float16)a, (_Float16)b };
    return t.u;
}
__device__ __forceinline__ uint16_t f2h(float a) {
    union { _Float16 h; uint16_t u; } t; t.h = (_Float16)a; return t.u;
}

__device__ __forceinline__ uint64_t sm64(uint64_t x) {
    x += 0x9E3779B97F4A7C15ULL;
    x = (x ^ (x >> 30)) * 0xBF58476D1CE4E5B9ULL;
    x = (x ^ (x >> 27)) * 0x94D049BB133111EBULL;
    return x ^ (x >> 31);
}

__device__ __forceinline__ uint32_t rowz_of(uint32_t f, int dim, int S, int s) {
    uint32_t b = f & 31u;
    uint32_t r = f >> 5;
    uint32_t d, h, w;
    if (dim == 0) {
        w = r & 7u; h = (r >> 3) & 7u; d = (r >> 6) + (uint32_t)s;
    } else if (dim == 1) {
        w = r & 7u; uint32_t q = r >> 3;
        h = q % (uint32_t)S + (uint32_t)s; d = q / (uint32_t)S;
    } else {
        w = r % (uint32_t)S + (uint32_t)s; uint32_t q = r / (uint32_t)S;
        h = q & 7u; d = q >> 3;
    }
    return b * 512u + d * 64u + h * 8u + w;
}

// ---------------- kernels ----------------

// Merged pre-pass: blocks [0,4096) transpose+cast z/c to row-major fp16
// (vectorized float4 tile fill -- bit-identical to scalar); blocks
// [4096,4288) cast W to B-fragment order; blocks [4288,4293) zero accum.
__global__ __launch_bounds__(256) void k_prepall(const float* __restrict__ z,
                                                 const float* __restrict__ c,
                                                 const float* __restrict__ W,
                                                 uint16_t* __restrict__ zh,
                                                 uint16_t* __restrict__ cTh,
                                                 uint16_t* __restrict__ Whf,
                                                 float* sums_s, int* cnts_s) {
    const int bid = blockIdx.x;
    const int t = threadIdx.x;
    if (bid < 4096) {
        __shared__ float tile[32][65];
        const int zz = bid >> 6;
        const int b = zz & 31, isC = zz >> 5;
        const float* src = (isC ? c : z) + (size_t)b * 131072;
        const int p0 = (bid & 7) * 64, ch0 = ((bid >> 3) & 7) * 32;
        #pragma unroll
        for (int it = 0; it < 2; it++) {
            int f = t + it * 256;              // 0..511
            int chv = f >> 4, p4 = (f & 15) * 4;
            float4 v = *(const float4*)(src + (size_t)(ch0 + chv) * 512 + p0 + p4);
            tile[chv][p4 + 0] = v.x; tile[chv][p4 + 1] = v.y;
            tile[chv][p4 + 2] = v.z; tile[chv][p4 + 3] = v.w;
        }
        __syncthreads();
        const int ml = t >> 2, ck = (t & 3) * 8;
        uint4 o;
        o.x = pk2h(tile[ck + 0][ml], tile[ck + 1][ml]);
        o.y = pk2h(tile[ck + 2][ml], tile[ck + 3][ml]);
        o.z = pk2h(tile[ck + 4][ml], tile[ck + 5][ml]);
        o.w = pk2h(tile[ck + 6][ml], tile[ck + 7][ml]);
        uint16_t* dst = isC ? cTh : zh;
        *(uint4*)(dst + (size_t)(b * 512 + p0 + ml) * 256 + ch0 + ck) = o;
    } else if (bid < 4288) {
        const int gid = (bid - 4096) * 4 + (t >> 6);
        const int lane = t & 63;
        const int kk = gid >> 7, rem = gid & 127;
        const int ks2 = rem >> 3, ot = rem & 7;
        const int o = ot * 32 + (lane & 31);
        const int cc = ks2 * 16 + (lane >> 5) * 8;
        const float* src = W + ((size_t)kk * 256 + o) * 256 + cc;
        float4 v0 = *(const float4*)src;
        float4 v1 = *(const float4*)(src + 4);
        uint4 out = make_uint4(pk2h(v0.x, v0.y), pk2h(v0.z, v0.w),
                               pk2h(v1.x, v1.y), pk2h(v1.z, v1.w));
        *(uint4*)(Whf + (size_t)gid * 512 + lane * 8) = out;
    } else {
        int t2 = (bid - 4288) * 256 + t;
        if (t2 < 1152) { sums_s[t2] = 0.f; cnts_s[t2] = 0; }
    }
}

// ZWh[kk][m][o] fp16 via 32x32x16 MFMA.
// v5: K=32 DMA double-buffer (16 MFMAs/barrier, 8 steps), 32 KB unioned
// smem, launch_bounds(256,2) -- UNCAPPED VGPR. R7 lesson: (256,3)'s ~170
// VGPR cap is below this kernel's natural ~180 footprint -> inner-loop
// scratch spills ate the occupancy gain. 2 blocks/CU with no spills is
// the measured optimum (R2 = 129.0 us config).
__global__ __launch_bounds__(256, 2) void k_gemm(const uint16_t* __restrict__ zh,
                                                 const uint16_t* __restrict__ Whf,
                                                 uint16_t* __restrict__ ZWh) {
    __shared__ __align__(16) uint16_t smem[16384];   // 32 KB: 2x16KB staging | 4x8KB epilogue
    const int kk = blockIdx.y;
    const int t = threadIdx.x, lane = t & 63, wv = t >> 6;
    const int m0 = blockIdx.x * 128 + wv * 32;
    const int col = lane & 31, hl = lane >> 5;
    const uint16_t* W32 = Whf + (size_t)kk * 65536;
    const uint16_t* A0 = zh + (size_t)(m0 + col) * 256 + hl * 8;

    f32x16 acc[8];
    #pragma unroll
    for (int i = 0; i < 8; i++)
        #pragma unroll
        for (int jj = 0; jj < 16; jj++) acc[i][jj] = 0.f;

    // stage the K=32 chunk `sk` (16 KB) into half `buf`; wave wv covers 4 KB
    #define BSTAGE(sk_, buf_) { \
        const char* gb_ = (const char*)W32 + (size_t)(sk_) * 16384 + wv * 4096 + lane * 16; \
        char* lb_ = (char*)smem + (buf_) * 16384 + wv * 4096; \
        _Pragma("unroll") \
        for (int i_ = 0; i_ < 4; i_++) \
            __builtin_amdgcn_global_load_lds( \
                (const __attribute__((address_space(1))) void*)(gb_ + i_ * 1024), \
                (__attribute__((address_space(3))) void*)(lb_ + i_ * 1024), 16, 0, 0); \
    }

    BSTAGE(0, 0);
    asm volatile("s_waitcnt vmcnt(0)" ::: "memory");
    __syncthreads();
    for (int sk = 0; sk < 8; sk++) {
        if (sk < 7) BSTAGE(sk + 1, (sk + 1) & 1);
        const uint16_t* Bb = smem + (sk & 1) * 8192;
        #pragma unroll
        for (int half = 0; half < 2; half++) {
            h8 a = *(const h8*)(A0 + (sk * 2 + half) * 16);
            const uint16_t* Bh = Bb + half * 4096;
            #pragma unroll
            for (int ot = 0; ot < 8; ot++) {
                h8 bv = *(const h8*)(&Bh[ot * 512 + lane * 8]);
                acc[ot] = __builtin_amdgcn_mfma_f32_32x32x16_f16(a, bv, acc[ot], 0, 0, 0);
            }
        }
        asm volatile("s_waitcnt vmcnt(0)" ::: "memory");
        __syncthreads();
    }
    #undef BSTAGE

    // fp16 epilogue: per-wave 8 KB tile in (reused) staging LDS
    uint16_t* Lb = smem + wv * 4096;
    uint16_t* dstbase = ZWh + ((size_t)kk * 16384 + m0) * 256;
    #pragma unroll
    for (int hh = 0; hh < 2; hh++) {
        #pragma unroll
        for (int ot = 0; ot < 8; ot++)
            #pragma unroll
            for (int rg = 0; rg < 8; rg++) {
                int reg = hh * 8 + rg;
                int row = (reg & 3) + 8 * (reg >> 2) + 4 * hl;
                Lb[(row - hh * 16) * 256 + ot * 32 + col] = f2h(acc[ot][reg]);
            }
        const uint4* Lr = (const uint4*)Lb;
        uint4* dst = (uint4*)(dstbase + hh * 16 * 256);
        #pragma unroll
        for (int i = 0; i < 8; i++)
            dst[i * 64 + lane] = Lr[i * 64 + lane];
    }
}

// Score v12 -- verbatim round-2 version (no ticket, no fence, no tail).
// R4 lesson: the fused-final tail (isLast + __syncthreads in divergent CF +
// __threadfence) collapsed codegen to VGPR=28 (fragments in scratch) and
// tripled runtime. Keep the epilogue as a separate tiny kernel.
__global__ __launch_bounds__(256, 4) void k_score(const uint16_t* __restrict__ ZWh,
                                                  const uint16_t* __restrict__ cTh,
                                                  const int* __restrict__ ign,
                                                  float* sums_s, int* cnts_s) {
    __shared__ float sbuf[4][288];
    __shared__ float wsum[4], wcnt[4];
    int bid = blockIdx.x;
    int kk = 0, cum = 0;
    for (;;) { int nb = 96 * (6 - kk); if (bid < cum + nb) break; cum += nb; kk++; }
    const int S = 6 - kk, T = S * 2048, s = kk + 2;
    const uint16_t* ZW = ZWh + (size_t)kk * 16384 * 256;

    const int local = bid - cum;
    const int dim = local / (32 * S);
    const int loc2 = local - dim * 32 * S;
    const int term = dim * 6 + kk;

    const int t = threadIdx.x, lane = t & 63, wv = t >> 6;
    const int lm = lane & 15, lq = lane >> 4;
    const uint32_t gidx = (uint32_t)(loc2 * 4 + wv);
    const uint32_t b = gidx & 31u;
    const uint32_t rb = gidx >> 5;
    const uint32_t r = rb * 16u + (uint32_t)lm;   // row slot lm's position

    uint32_t d, h, w;
    if (dim == 0)      { w = r & 7u; h = (r >> 3) & 7u; d = r >> 6; }
    else if (dim == 1) { w = r & 7u; uint32_t qq = r >> 3; h = qq % (uint32_t)S; d = qq / (uint32_t)S; }
    else               { w = r % (uint32_t)S; uint32_t qq = r / (uint32_t)S; h = qq & 7u; d = qq >> 3; }
    uint32_t pc = d * 64u + h * 8u + w;
    uint32_t pz = pc + (dim == 0 ? (uint32_t)s * 64u : dim == 1 ? (uint32_t)s * 8u : (uint32_t)s);
    uint32_t rowc = b * 512u + pc;
    uint32_t rowz = b * 512u + pz;

    // one shared negative row per slot lm (same sm64 stream family, set j=0)
    uint64_t x = sm64(((uint64_t)term << 40) +
                      (uint64_t)gidx * 128u + (uint64_t)lm);
    uint32_t nrow = rowz_of((uint32_t)(x >> 32) % (uint32_t)T, dim, S, s);

    int mok = (ign[rowc] + ign[rowz]) == 0;

    // per-lane fragment bases: row (lane&15), 8 fp16 at k = ks*32 + lq*8
    const uint16_t* cA = cTh + (size_t)rowc * 256 + lq * 8;
    const uint16_t* pB = ZW + (size_t)rowz * 256 + lq * 8;
    const uint16_t* nB = ZW + (size_t)nrow * 256 + lq * 8;

    h8 af[8], pf[8], nf[8];
    #pragma unroll
    for (int ks = 0; ks < 8; ks++) af[ks] = *(const h8*)(cA + ks * 32);
    #pragma unroll
    for (int ks = 0; ks < 8; ks++) pf[ks] = *(const h8*)(pB + ks * 32);
    #pragma unroll
    for (int ks = 0; ks < 8; ks++) nf[ks] = *(const h8*)(nB + ks * 32);

    f32x4 accp = (f32x4){0.f, 0.f, 0.f, 0.f};
    f32x4 accn = (f32x4){0.f, 0.f, 0.f, 0.f};
    #pragma unroll
    for (int ks = 0; ks < 8; ks++)
        accp = __builtin_amdgcn_mfma_f32_16x16x32_f16(af[ks], pf[ks], accp, 0, 0, 0);
    #pragma unroll
    for (int ks = 0; ks < 8; ks++)
        accn = __builtin_amdgcn_mfma_f32_16x16x32_f16(af[ks], nf[ks], accn, 0, 0, 0);

    // scatter scores: D[m][n] with m = lq*4+reg, n = lm
    float* Sb = sbuf[wv];
    #pragma unroll
    for (int rg = 0; rg < 4; rg++)
        Sb[(lq * 4 + rg) * 17 + lm] = accn[rg];
    if ((lm >> 2) == lq) Sb[272 + lm] = accp[lm & 3];

    // softmax-NLL for position p = lm (4x redundant across lq)
    float dpos = Sb[272 + lm];
    float mx = dpos;
    float scn[16];
    #pragma unroll
    for (int n = 0; n < 16; n++) { scn[n] = Sb[lm * 17 + n]; mx = fmaxf(mx, scn[n]); }
    float e0 = __expf(dpos - mx), sum = e0;
    #pragma unroll
    for (int n = 0; n < 16; n++) sum += __expf(scn[n] - mx);
    float nll = -__logf(e0 / sum + EPSL);

    float v = mok ? nll : 0.f;
    float cm = mok ? 1.f : 0.f;
    #pragma unroll
    for (int st = 1; st < 64; st <<= 1) {
        v  += __shfl_xor(v, st, 64);
        cm += __shfl_xor(cm, st, 64);
    }
    if (lane == 0) { wsum[wv] = v * 0.25f; wcnt[wv] = cm * 0.25f; }
    __syncthreads();
    if (t == 0) {
        float sv = wsum[0] + wsum[1] + wsum[2] + wsum[3];
        float cv = wcnt[0] + wcnt[1] + wcnt[2] + wcnt[3];
        int slot = blockIdx.x & 63;
        atomicAdd(&sums_s[term * 64 + slot], sv);
        atomicAdd(&cnts_s[term * 64 + slot], (int)(cv + 0.5f));
    }
}

__global__ void k_final(const float* __restrict__ sums_s, const int* __restrict__ cnts_s,
                        float* __restrict__ out) {
    __shared__ float ratio[18];
    int t = threadIdx.x;
    if (t < 18) {
        float sv = 0.f; int cv = 0;
        #pragma unroll 8
        for (int i = 0; i < 64; i++) { sv += sums_s[t * 64 + i]; cv += cnts_s[t * 64 + i]; }
        ratio[t] = sv / (float)cv;
    }
    __syncthreads();
    if (t == 0) {
        float tot = 0.f;
        #pragma unroll
        for (int i = 0; i < 18; i++) tot += ratio[i];
        out[0] = tot / 18.f;
    }
}

// ---------------- launch ----------------
extern "C" void kernel_launch(void* const* d_in, const int* in_sizes, int n_in,
                              void* d_out, int out_size, void* d_ws, size_t ws_size,
                              hipStream_t stream) {
    const float* z   = (const float*)d_in[0];
    const float* c   = (const float*)d_in[1];
    const int*   ign = (const int*)d_in[2];
    const float* Wk  = (const float*)d_in[3];

    float* sums_s = (float*)d_ws;                           // 18*64 floats
    int*   cnts_s = (int*)((char*)d_ws + 4608);             // 18*64 ints
    uint16_t* zh  = (uint16_t*)((char*)d_ws + 65536);       // 8 MiB row-major fp16
    uint16_t* cTh = zh  + (size_t)16384 * 256;              // 8 MiB row-major fp16
    uint16_t* Whf = cTh + (size_t)16384 * 256;              // 768 KiB B-frag order
    uint16_t* ZWh = Whf + (size_t)6 * 65536;                // 48 MiB row-major fp16

    hipLaunchKernelGGL(k_prepall, dim3(4293), dim3(256), 0, stream,
                       z, c, Wk, zh, cTh, Whf, sums_s, cnts_s);
    hipLaunchKernelGGL(k_gemm, dim3(128, 6), dim3(256), 0, stream, zh, Whf, ZWh);
    hipLaunchKernelGGL(k_score, dim3(2016), dim3(256), 0, stream, ZWh, cTh, ign, sums_s, cnts_s);
    hipLaunchKernelGGL(k_final, dim3(1), dim3(64), 0, stream, sums_s, cnts_s, (float*)d_out);
}